// Round 11
// baseline (171.857 us; speedup 1.0000x reference)
//
#include <hip/hip_runtime.h>
#include <hip/hip_bf16.h>

typedef short short8 __attribute__((ext_vector_type(8)));
typedef short short4v __attribute__((ext_vector_type(4)));
typedef int i32x4 __attribute__((ext_vector_type(4)));
typedef float f32x4 __attribute__((ext_vector_type(4)));

#define MFMA(a, b, c) __builtin_amdgcn_mfma_f32_16x16x32_bf16((a), (b), (c), 0, 0, 0)

__device__ __forceinline__ short f2bf(float f) {
  unsigned u = __builtin_bit_cast(unsigned, f);
  unsigned r = u + 0x7FFFu + ((u >> 16) & 1u);
  return (short)(r >> 16);
}

__device__ __forceinline__ float bf2f(short s) {
  unsigned u = ((unsigned)(unsigned short)s) << 16;
  return __builtin_bit_cast(float, u);
}

__device__ __forceinline__ short8 cvt8(float4 a, float4 b) {
  short8 t;
  t[0] = f2bf(a.x); t[1] = f2bf(a.y); t[2] = f2bf(a.z); t[3] = f2bf(a.w);
  t[4] = f2bf(b.x); t[5] = f2bf(b.y); t[6] = f2bf(b.z); t[7] = f2bf(b.w);
  return t;
}

// ---------------- Kernel 0: weight prep only (bf16 casts + pkT) -------------
__global__ __launch_bounds__(256) void k_prep(
    const float* __restrict__ wq, const float* __restrict__ wk,
    const float* __restrict__ wout, const float* __restrict__ pk,
    short* __restrict__ wqb, short* __restrict__ wkb,
    short* __restrict__ woutb, short* __restrict__ pkT)
{
  int idx = blockIdx.x * 256 + threadIdx.x;
  if (idx < 147456) { wqb[idx] = f2bf(wq[idx]); wkb[idx] = f2bf(wk[idx]); }
  if (idx < 589824) { woutb[idx] = f2bf(wout[idx]); }
  if (idx < 524288) {
    int n = idx >> 8, k = idx & 255;              // pk is [n][k]
    pkT[(size_t)k * 2048 + n] = f2bf(pk[idx]);    // pkT is [k][n]
  }
}

// ---------------- Kernel 1: grouped conv (queries only) ---------------------
// R5-best structure. xbT ELIMINATED: k_xproj now transposes natural x in its
// own LDS staging, so k_conv drops the 6-phase transpose gather + 25MB of
// HBM writes (WRITE_SIZE 49.6 -> ~25MB). Everything kept else byte-identical
// (6 structural k_conv variants R5-R10 all failed; removing work is the
// remaining lever).
__global__ __launch_bounds__(256, 2) void k_conv(
    const float* __restrict__ x, const short* __restrict__ wqb,
    short* __restrict__ qo)
{
  __shared__ __align__(16) short Xs[64 * 192];    // swizzled [r][octet^sw(r)]
  const int tid = threadIdx.x, lane = tid & 63, w = tid >> 6;
  const int g = blockIdx.y;
  const int m0 = blockIdx.x * 64;                 // global row (b*2048+n)
  const int wr = (w >> 1) * 32, wcol = (w & 1) * 96;
  const int lrow = lane & 15, g4 = lane >> 4, lk8 = g4 * 8;

  // ---- stage full tile (bf16, swizzled), quad-contiguous 128B chunks ----
  {
    const int r = tid >> 2, q = tid & 3;
    const int sw = (r ^ (r >> 3)) & 7;
    const float* src = x + (size_t)(m0 + r) * 768 + g * 192;
#pragma unroll
    for (int i = 0; i < 6; i++) {
      const int col = i * 32 + q * 8;             // 4 lanes -> 128B contig
      float4 v0 = *(const float4*)(src + col);
      float4 v1 = *(const float4*)(src + col + 4);
      const int o = col >> 3;                     // octet = i*4 + q
      *(short8*)&Xs[r * 192 + ((o ^ sw) << 3)] = cvt8(v0, v1);
    }
  }
  __syncthreads();

  f32x4 acc[2][6];
#pragma unroll
  for (int mi = 0; mi < 2; mi++)
#pragma unroll
    for (int cf = 0; cf < 6; cf++) acc[mi][cf] = (f32x4)0.f;

  const int row0 = wr + lrow, row1 = wr + 16 + lrow;
  const int sw0 = (row0 ^ (row0 >> 3)) & 7;
  const int sw1 = (row1 ^ (row1 >> 3)) & 7;

#pragma unroll
  for (int s = 0; s < 6; s++) {
    const int k0 = s * 32;
    const int ob = (k0 >> 3) + g4;
    short8 a0 = *(const short8*)&Xs[row0 * 192 + ((ob ^ sw0) << 3)];
    short8 a1 = *(const short8*)&Xs[row1 * 192 + ((ob ^ sw1) << 3)];
#pragma unroll
    for (int cf = 0; cf < 6; cf++) {
      short8 bb = *(const short8*)(wqb + ((size_t)g * 192 + wcol + cf * 16 + lrow) * 192 + k0 + lk8);
      acc[0][cf] = MFMA(a0, bb, acc[0][cf]);
      acc[1][cf] = MFMA(a1, bb, acc[1][cf]);
    }
  }

  // ---- queries out ----
#pragma unroll
  for (int mi = 0; mi < 2; mi++)
#pragma unroll
    for (int cf = 0; cf < 6; cf++)
#pragma unroll
      for (int j = 0; j < 4; j++) {
        int m = m0 + wr + mi * 16 + g4 * 4 + j;
        qo[(size_t)m * 768 + g * 192 + wcol + cf * 16 + lrow] = f2bf(acc[mi][cf][j]);
      }
}

// ---------------- Kernel 2: xproj[b,k2,e] = sum_n pk[n,k2] * x[b,n,e] -------
// B operand now staged DIRECTLY from natural-layout fp32 x (no xbT):
// thread (e=lane, n8=wave) reads 8 column floats (stride 3072B, coalesced
// 256B/inst across lanes), cvt -> one short8 -> octet-XOR-swizzled
// B2[e][n8^..] write (~2-way banks on both write and fragment read = free).
// x is L3-hot right after k_conv, so these reads are mostly cache hits.
__global__ __launch_bounds__(512, 4) void k_xproj(
    const short* __restrict__ pkT, const float* __restrict__ x,
    float* __restrict__ xproj)
{
  __shared__ __align__(16) short A2[2][64][72];
  __shared__ __align__(16) short B2[2][64][72];
  const int tid = threadIdx.x, lane = tid & 63, w = tid >> 6;
  const int f = blockIdx.x;
  const int xcd = f & 7, rem = f >> 3;
  const int k2t4 = rem & 3, eb8 = rem >> 2;
  const int e_b = eb8 * 8 + xcd;             // [0,96)
  const int k2t = k2t4 * 64;
  const int et = (e_b % 12) * 64, b = e_b / 12;
  const int lrow = lane & 15, g4 = lane >> 4, lk8 = g4 * 8;
  const int wa = (w & 3) * 16, wb = (w >> 2) * 32;

  // A staging (unchanged): thread r=tid>>3 stages row r, octet c8
  const int r = tid >> 3, c8 = tid & 7;
  const short* aSrc = pkT + (size_t)(k2t + r) * 2048 + c8 * 8;

  // B staging (new): e = lane, n-octet = wave
  const int se = tid & 63, sn8 = tid >> 6;
  const int sb8 = (sn8 ^ (se & 7)) * 8;      // swizzled octet offset (shorts)
  const float* bSrc = x + ((size_t)b * 2048 + sn8 * 8) * 768 + et + se;

  {
    short8 gA = *(const short8*)aSrc;
    *(short8*)&A2[0][r][c8 * 8] = gA;
    float4 f0, f1;
    f0.x = bSrc[0 * 768]; f0.y = bSrc[1 * 768];
    f0.z = bSrc[2 * 768]; f0.w = bSrc[3 * 768];
    f1.x = bSrc[4 * 768]; f1.y = bSrc[5 * 768];
    f1.z = bSrc[6 * 768]; f1.w = bSrc[7 * 768];
    *(short8*)&B2[0][se][sb8] = cvt8(f0, f1);
  }
  __syncthreads();

  f32x4 acc[2];
  acc[0] = (f32x4)0.f; acc[1] = (f32x4)0.f;

  // swizzled B-octet offsets for the 4 fragment reads (row-dependent)
  const int rB0 = wb + lrow, rB1 = wb + 16 + lrow;
  const int oB00 = ((g4) ^ (rB0 & 7)) * 8, oB01 = ((4 + g4) ^ (rB0 & 7)) * 8;
  const int oB10 = ((g4) ^ (rB1 & 7)) * 8, oB11 = ((4 + g4) ^ (rB1 & 7)) * 8;

  short8 gA;
  float gB[8];
#pragma unroll 2
  for (int t = 0; t < 32; ++t) {
    const int cur = t & 1;
    if (t < 31) {
      gA = *(const short8*)(aSrc + (t + 1) * 64);
      const float* bs = bSrc + (size_t)(t + 1) * 64 * 768;
#pragma unroll
      for (int i = 0; i < 8; i++) gB[i] = bs[i * 768];
    }
    short8 af0 = *(const short8*)&A2[cur][wa + lrow][lk8];
    short8 af1 = *(const short8*)&A2[cur][wa + lrow][32 + lk8];
    short8 bf00 = *(const short8*)&B2[cur][rB0][oB00];
    short8 bf01 = *(const short8*)&B2[cur][rB0][oB01];
    short8 bf10 = *(const short8*)&B2[cur][rB1][oB10];
    short8 bf11 = *(const short8*)&B2[cur][rB1][oB11];
    acc[0] = MFMA(af0, bf00, acc[0]);
    acc[0] = MFMA(af1, bf01, acc[0]);
    acc[1] = MFMA(af0, bf10, acc[1]);
    acc[1] = MFMA(af1, bf11, acc[1]);
    if (t < 31) {
      *(short8*)&A2[cur ^ 1][r][c8 * 8] = gA;
      float4 f0, f1;
      f0.x = gB[0]; f0.y = gB[1]; f0.z = gB[2]; f0.w = gB[3];
      f1.x = gB[4]; f1.y = gB[5]; f1.z = gB[6]; f1.w = gB[7];
      *(short8*)&B2[cur ^ 1][se][sb8] = cvt8(f0, f1);
    }
    __syncthreads();
  }

  float* dst = xproj + ((size_t)b * 256 + k2t + wa) * 768 + et + wb;
#pragma unroll
  for (int cf = 0; cf < 2; cf++)
#pragma unroll
    for (int j = 0; j < 4; j++)
      dst[(size_t)(g4 * 4 + j) * 768 + cf * 16 + lrow] = acc[cf][j];
}

// ---------------- Kernel 2.5: kp = grouped conv_k(xproj), IN-PLACE ----------
__global__ __launch_bounds__(256) void k_kconv(
    float* xpio, const short* __restrict__ wkb)
{
  const int tid = threadIdx.x, lane = tid & 63, w = tid >> 6;
  const int rt = blockIdx.x * 64, g = blockIdx.y, b = blockIdx.z;
  const int wr = (w >> 1) * 32, wcol = (w & 1) * 96;
  const int lrow = lane & 15, g4 = lane >> 4, lk8 = (lane >> 4) * 8;

  f32x4 acc[2][6];
#pragma unroll
  for (int mi = 0; mi < 2; mi++)
#pragma unroll
    for (int cf = 0; cf < 6; cf++) acc[mi][cf] = (f32x4)0.f;

#pragma unroll
  for (int s = 0; s < 6; s++) {
    int k0 = s * 32;
    short8 af[2];
#pragma unroll
    for (int mi = 0; mi < 2; mi++) {
      const float* ap = xpio + ((size_t)b * 256 + rt + wr + mi * 16 + lrow) * 768
                        + g * 192 + k0 + lk8;
      float4 f0 = *(const float4*)ap;
      float4 f1 = *(const float4*)(ap + 4);
      af[mi] = cvt8(f0, f1);
    }
#pragma unroll
    for (int cf = 0; cf < 6; cf++) {
      short8 bb = *(const short8*)(wkb + ((size_t)g * 192 + wcol + cf * 16 + lrow) * 192 + k0 + lk8);
      acc[0][cf] = MFMA(af[0], bb, acc[0][cf]);
      acc[1][cf] = MFMA(af[1], bb, acc[1][cf]);
    }
  }
  __syncthreads();   // all waves' reads of this block's region complete
#pragma unroll
  for (int mi = 0; mi < 2; mi++)
#pragma unroll
    for (int cf = 0; cf < 6; cf++)
#pragma unroll
      for (int j = 0; j < 4; j++) {
        int k2 = rt + wr + mi * 16 + g4 * 4 + j;
        xpio[((size_t)b * 256 + k2) * 768 + g * 192 + wcol + cf * 16 + lrow] =
            acc[mi][cf][j];
      }
}

// ---------------- Kernel 3: gather K/V per (b,h) into bf16 staging ----------
__global__ __launch_bounds__(256) void k_gather(
    const float* __restrict__ kp, short* __restrict__ Kb, short* __restrict__ Vb)
{
  const int h = blockIdx.x, b = blockIdx.y;
  const int bh = b * 12 + h;
  const int tid = threadIdx.x;
  const float* kpb = kp + (size_t)b * 196608;
  {
    const int kb4 = (h & 3) * 64, doff = h >> 2;
    const int dh = tid & 63, kq = tid >> 6;   // kq uniform per wave
    const float* row = kpb + (size_t)(kb4 + dh) * 768 + doff;
    short* dst = Kb + (size_t)bh * 18432 + dh;
#pragma unroll 8
    for (int i = 0; i < 64; i++) {
      int k2 = kq * 64 + i;
      dst[(size_t)k2 * 72] = f2bf(row[3 * k2]);   // coalesced 128B store
    }
  }
  {
    short* dst = Vb + (size_t)bh * 16384;
#pragma unroll
    for (int i = 0; i < 8; i++) {
      int oct = tid + 256 * i;
      int k2h = oct >> 6, dh = oct & 63;        // dh = lane -> coalesced reads
      short8 v;
#pragma unroll
      for (int u = 0; u < 8; u++)
        v[u] = f2bf(kpb[(size_t)(k2h * 8 + u) * 768 + h * 64 + dh]);
      *(short8*)&dst[oct * 8] = v;              // coalesced 16B store
    }
  }
}

// ---------------- Kernel 4: attention per (b,h) -----------------------------
__global__ __launch_bounds__(512, 4) void k_attn(
    const short* __restrict__ qws, const short* __restrict__ Kb,
    const short* __restrict__ Vb, short* __restrict__ ctx)
{
  __shared__ __align__(16) short Kls[18432];   // [k2][72]
  __shared__ __align__(16) short Vls[16384];   // [k2>>3][dh][k2&7]
  const int tid = threadIdx.x, lane = tid & 63, w = tid >> 6;
  const int n0 = blockIdx.x * 128;
  const int h = blockIdx.y, b = blockIdx.z;
  const int bh = b * 12 + h;

  {
    const short8* gk = (const short8*)(Kb + (size_t)bh * 18432);
    short8* lk = (short8*)Kls;
#pragma unroll
    for (int i = 0; i < 4; i++) lk[tid + 512 * i] = gk[tid + 512 * i];
    if (tid < 256) lk[tid + 2048] = gk[tid + 2048];
    const short8* gv = (const short8*)(Vb + (size_t)bh * 16384);
    short8* lv = (short8*)Vls;
#pragma unroll
    for (int i = 0; i < 4; i++) lv[tid + 512 * i] = gv[tid + 512 * i];
  }
  const int lrow = lane & 15, g = lane >> 4, lk8 = g * 8;
  const int nrow = n0 + w * 16;
  const short* qp = qws + ((size_t)b * 2048 + nrow + lrow) * 768 + h * 64;
  short8 bq0 = *(const short8*)(qp + lk8);
  short8 bq1 = *(const short8*)(qp + 32 + lk8);
  __syncthreads();

  f32x4 s[16];
#pragma unroll
  for (int fc = 0; fc < 16; fc++) s[fc] = (f32x4)0.f;
  __builtin_amdgcn_s_setprio(1);
#pragma unroll
  for (int fc = 0; fc < 16; fc++) {
    short8 ak0 = *(const short8*)&Kls[(fc * 16 + lrow) * 72 + lk8];
    short8 ak1 = *(const short8*)&Kls[(fc * 16 + lrow) * 72 + 32 + lk8];
    s[fc] = MFMA(ak0, bq0, s[fc]);
    s[fc] = MFMA(ak1, bq1, s[fc]);
  }
  __builtin_amdgcn_s_setprio(0);

  float mx = -3.0e38f;
#pragma unroll
  for (int fc = 0; fc < 16; fc++)
#pragma unroll
    for (int j = 0; j < 4; j++) mx = fmaxf(mx, s[fc][j]);
  mx = fmaxf(mx, __shfl_xor(mx, 16));
  mx = fmaxf(mx, __shfl_xor(mx, 32));
  float sum = 0.f;
#pragma unroll
  for (int fc = 0; fc < 16; fc++)
#pragma unroll
    for (int j = 0; j < 4; j++) {
      float e = __expf(0.125f * (s[fc][j] - mx));
      s[fc][j] = e; sum += e;
    }
  sum += __shfl_xor(sum, 16);
  sum += __shfl_xor(sum, 32);
  float inv = 1.f / sum;

  unsigned pku[16][2];
#pragma unroll
  for (int fc = 0; fc < 16; fc++) {
    pku[fc][0] = (unsigned)(unsigned short)f2bf(s[fc][0] * inv)
               | ((unsigned)(unsigned short)f2bf(s[fc][1] * inv) << 16);
    pku[fc][1] = (unsigned)(unsigned short)f2bf(s[fc][2] * inv)
               | ((unsigned)(unsigned short)f2bf(s[fc][3] * inv) << 16);
  }

  f32x4 o[4];
#pragma unroll
  for (int fd = 0; fd < 4; fd++) o[fd] = (f32x4)0.f;
  const int L0 = ((lane & 16) << 1) + lrow;   // 32*(g&1) + c
  const int L1 = L0 + 16;
  const bool hi = (lane >= 32);               // fc select = g>>1
  __builtin_amdgcn_s_setprio(1);
#pragma unroll
  for (int t = 0; t < 8; t++) {
    unsigned a0 = (unsigned)__shfl((int)pku[2 * t][0], L0);
    unsigned a1 = (unsigned)__shfl((int)pku[2 * t][1], L0);
    unsigned a2 = (unsigned)__shfl((int)pku[2 * t][0], L1);
    unsigned a3 = (unsigned)__shfl((int)pku[2 * t][1], L1);
    unsigned c0 = (unsigned)__shfl((int)pku[2 * t + 1][0], L0);
    unsigned c1 = (unsigned)__shfl((int)pku[2 * t + 1][1], L0);
    unsigned c2 = (unsigned)__shfl((int)pku[2 * t + 1][0], L1);
    unsigned c3 = (unsigned)__shfl((int)pku[2 * t + 1][1], L1);
    i32x4 bi = { (int)(hi ? c0 : a0), (int)(hi ? c1 : a1),
                 (int)(hi ? c2 : a2), (int)(hi ? c3 : a3) };
    short8 bfrag = __builtin_bit_cast(short8, bi);
#pragma unroll
    for (int fd = 0; fd < 4; fd++) {
      short8 av = *(const short8*)&Vls[((t * 4 + g) * 64 + fd * 16 + lrow) * 8];
      o[fd] = MFMA(av, bfrag, o[fd]);
    }
  }
  __builtin_amdgcn_s_setprio(0);
#pragma unroll
  for (int fd = 0; fd < 4; fd++) {
    short4v st;
#pragma unroll
    for (int j = 0; j < 4; j++) st[j] = f2bf(o[fd][j]);
    *(short4v*)&ctx[((size_t)b * 2048 + n0 + w * 16 + lrow) * 768
                    + h * 64 + fd * 16 + 4 * g] = st;
  }
}

// ---------------- Kernel 5: y = ctx@Wout^T + bias + x  (bf16 y) -------------
// 128x128 tile, BK=32, reg->LDS dbuf. grid 768 = 3 blocks/CU; XCD-swizzled.
__global__ __launch_bounds__(512, 4) void k_gemm_y(
    const short* __restrict__ ctx, const short* __restrict__ woutb,
    const float* __restrict__ bout, const float* __restrict__ x,
    short* __restrict__ ybf)
{
  __shared__ __align__(16) short As[2][128][40];
  __shared__ __align__(16) short Bs[2][128][40];
  const int tid = threadIdx.x, lane = tid & 63, w = tid >> 6;
  const int f = blockIdx.x;
  const int xcd = f & 7, rem = f >> 3;       // rem in [0,96)
  const int mi_l = rem / 6, ni = rem % 6;
  const int m0 = (xcd * 16 + mi_l) * 128;
  const int n0 = ni * 128;
  const int lrow = lane & 15, g4 = lane >> 4, lk8 = g4 * 8;
  const int wr2 = (w >> 2) * 64, wc4 = (w & 3) * 32;

  const int r = tid >> 2, c8 = (tid & 3) * 8;
  const short* aSrc = ctx + (size_t)(m0 + r) * 768 + c8;
  const short* bSrc = woutb + (size_t)(n0 + r) * 768 + c8;

  {
    short8 gA = *(const short8*)aSrc;
    short8 gB = *(const short8*)bSrc;
    *(short8*)&As[0][r][c8] = gA;
    *(short8*)&Bs[0][r][c8] = gB;
  }
  __syncthreads();

  f32x4 acc[4][2];
#pragma unroll
  for (int rf = 0; rf < 4; rf++)
#pragma unroll
    for (int cf = 0; cf < 2; cf++) acc[rf][cf] = (f32x4)0.f;

  short8 gA, gB;
#pragma unroll 2
  for (int t = 0; t < 24; ++t) {
    const int cur = t & 1;
    if (t < 23) {
      gA = *(const short8*)(aSrc + (t + 1) * 32);
      gB = *(const short8*)(bSrc + (t + 1) * 32);
    }
    short8 af[4], bf[2];
#pragma unroll
    for (int rf = 0; rf < 4; rf++)
      af[rf] = *(const short8*)&As[cur][wr2 + rf * 16 + lrow][lk8];
#pragma unroll
    for (int cf = 0; cf < 2; cf++)
      bf[cf] = *(const short8*)&Bs[cur][wc4 + cf * 16 + lrow][lk8];
#pragma unroll
    for (int cf = 0; cf < 2; cf++)
#pragma unroll
      for (int rf = 0; rf < 4; rf++)
        acc[rf][cf] = MFMA(af[rf], bf[cf], acc[rf][cf]);
    if (t < 23) {
      *(short8*)&As[cur ^ 1][r][c8] = gA;
      *(short8*)&Bs[cur ^ 1][r][c8] = gB;
    }
    __syncthreads();
  }

  float cB[2];
#pragma unroll
  for (int cf = 0; cf < 2; cf++) cB[cf] = bout[n0 + wc4 + cf * 16 + lrow];
#pragma unroll
  for (int rf = 0; rf < 4; rf++)
#pragma unroll
    for (int j = 0; j < 4; j++) {
      int row = m0 + wr2 + rf * 16 + g4 * 4 + j;
      const float* xr = x + (size_t)row * 768 + n0 + wc4;
      short* yr = ybf + (size_t)row * 768 + n0 + wc4;
#pragma unroll
      for (int cf = 0; cf < 2; cf++)
        yr[cf * 16 + lrow] = f2bf(acc[rf][cf][j] + cB[cf] + xr[cf * 16 + lrow]);
    }
}

// ---------------- Kernel 6: LayerNorm over bf16 y -> fp32 out ---------------
__global__ __launch_bounds__(256) void k_ln(
    const short* __restrict__ ybf, const float* __restrict__ gamma,
    const float* __restrict__ beta, float* __restrict__ out)
{
  const int tid = threadIdx.x, lane = tid & 63, w = tid >> 6;
  const int half = lane >> 5, l5 = lane & 31;
  const int row = blockIdx.x * 8 + w * 2 + half;
  const short* yr = ybf + (size_t)row * 768;

  float v[24];
  float s1 = 0.f, s2 = 0.f;
#pragma unroll
  for (int j = 0; j < 3; j++) {
    short8 p = *(const short8*)(yr + (l5 + 32 * j) * 8);
#pragma unroll
    for (int u = 0; u < 8; u++) {
      float fv = bf2f(p[u]);
      v[j * 8 + u] = fv;
      s1 += fv; s2 += fv * fv;
    }
  }
  s1 += __shfl_xor(s1, 1, 32);  s2 += __shfl_xor(s2, 1, 32);
  s1 += __shfl_xor(s1, 2, 32);  s2 += __shfl_xor(s2, 2, 32);
  s1 += __shfl_xor(s1, 4, 32);  s2 += __shfl_xor(s2, 4, 32);
  s1 += __shfl_xor(s1, 8, 32);  s2 += __shfl_xor(s2, 8, 32);
  s1 += __shfl_xor(s1, 16, 32); s2 += __shfl_xor(s2, 16, 32);
  float mean = s1 * (1.f / 768.f);
  float var = s2 * (1.f / 768.f) - mean * mean;
  float rstd = rsqrtf(var + 1e-12f);

  float* orow = out + (size_t)row * 768;
#pragma unroll
  for (int j = 0; j < 3; j++) {
    int c0 = (l5 + 32 * j) * 8;
    float4 o0, o1;
    o0.x = (v[j*8+0] - mean) * rstd * gamma[c0+0] + beta[c0+0];
    o0.y = (v[j*8+1] - mean) * rstd * gamma[c0+1] + beta[c0+1];
    o0.z = (v[j*8+2] - mean) * rstd * gamma[c0+2] + beta[c0+2];
    o0.w = (v[j*8+3] - mean) * rstd * gamma[c0+3] + beta[c0+3];
    o1.x = (v[j*8+4] - mean) * rstd * gamma[c0+4] + beta[c0+4];
    o1.y = (v[j*8+5] - mean) * rstd * gamma[c0+5] + beta[c0+5];
    o1.z = (v[j*8+6] - mean) * rstd * gamma[c0+6] + beta[c0+6];
    o1.w = (v[j*8+7] - mean) * rstd * gamma[c0+7] + beta[c0+7];
    *(float4*)(orow + c0) = o0;
    *(float4*)(orow + c0 + 4) = o1;
  }
}

// ---------------- Launch ----------------------------------------------------
extern "C" void kernel_launch(void* const* d_in, const int* in_sizes, int n_in,
                              void* d_out, int out_size, void* d_ws, size_t ws_size,
                              hipStream_t stream)
{
  const float* x     = (const float*)d_in[0];
  const float* wq    = (const float*)d_in[1];
  const float* wk    = (const float*)d_in[2];
  const float* pk    = (const float*)d_in[3];
  const float* wout  = (const float*)d_in[4];
  const float* bout  = (const float*)d_in[5];
  const float* gamma = (const float*)d_in[6];
  const float* beta  = (const float*)d_in[7];
  float* out = (float*)d_out;

  char* ws = (char*)d_ws;
  short* qbf   = (short*)(ws + 0);           // 16384*768*2 = 25165824 (ybf after attn)
  short* ctx   = (short*)(ws + 25165824);    // 25165824 (xbT slot, now ctx only)
  float* kpbuf = (float*)(ws + 50331648);    // 6291456 (xproj then kp, in-place)
  short* wqb   = (short*)(ws + 56623104);    // 294912
  short* wkb   = (short*)(ws + 56918016);    // 294912
  short* woutb = (short*)(ws + 57212928);    // 1179648
  short* pkT   = (short*)(ws + 58392576);    // 1048576
  if (ws_size < 59441152) return;            // insufficient scratch: clean fail
  short* ybf = qbf;                          // qbf dead after k_attn

  short* Kb = (short*)d_out;                 // staging in d_out (dead after k_attn)
  short* Vb = Kb + 96 * 18432;

  k_prep<<<2304, 256, 0, stream>>>(wq, wk, wout, pk, wqb, wkb, woutb, pkT);
  k_conv<<<dim3(256, 4), 256, 0, stream>>>(x, wqb, qbf);
  k_xproj<<<384, 512, 0, stream>>>(pkT, x, kpbuf);
  k_kconv<<<dim3(4, 4, 8), 256, 0, stream>>>(kpbuf, wkb);
  k_gather<<<dim3(12, 8), 256, 0, stream>>>(kpbuf, Kb, Vb);
  k_attn<<<dim3(16, 12, 8), 512, 0, stream>>>(qbf, Kb, Vb, ctx);
  k_gemm_y<<<768, 512, 0, stream>>>(ctx, woutb, bout, x, ybf);
  k_ln<<<2048, 256, 0, stream>>>(ybf, gamma, beta, out);
}

// Round 12
// 165.564 us; speedup vs baseline: 1.0380x; 1.0380x over previous
//
#include <hip/hip_runtime.h>
#include <hip/hip_bf16.h>

typedef short short8 __attribute__((ext_vector_type(8)));
typedef short short4v __attribute__((ext_vector_type(4)));
typedef int i32x4 __attribute__((ext_vector_type(4)));
typedef float f32x4 __attribute__((ext_vector_type(4)));

#define MFMA(a, b, c) __builtin_amdgcn_mfma_f32_16x16x32_bf16((a), (b), (c), 0, 0, 0)

__device__ __forceinline__ short f2bf(float f) {
  unsigned u = __builtin_bit_cast(unsigned, f);
  unsigned r = u + 0x7FFFu + ((u >> 16) & 1u);
  return (short)(r >> 16);
}

__device__ __forceinline__ float bf2f(short s) {
  unsigned u = ((unsigned)(unsigned short)s) << 16;
  return __builtin_bit_cast(float, u);
}

__device__ __forceinline__ short8 cvt8(float4 a, float4 b) {
  short8 t;
  t[0] = f2bf(a.x); t[1] = f2bf(a.y); t[2] = f2bf(a.z); t[3] = f2bf(a.w);
  t[4] = f2bf(b.x); t[5] = f2bf(b.y); t[6] = f2bf(b.z); t[7] = f2bf(b.w);
  return t;
}

// ---------------- Kernel 0: weight prep only (bf16 casts + pkT) -------------
__global__ __launch_bounds__(256) void k_prep(
    const float* __restrict__ wq, const float* __restrict__ wk,
    const float* __restrict__ wout, const float* __restrict__ pk,
    short* __restrict__ wqb, short* __restrict__ wkb,
    short* __restrict__ woutb, short* __restrict__ pkT)
{
  int idx = blockIdx.x * 256 + threadIdx.x;
  if (idx < 147456) { wqb[idx] = f2bf(wq[idx]); wkb[idx] = f2bf(wk[idx]); }
  if (idx < 589824) { woutb[idx] = f2bf(wout[idx]); }
  if (idx < 524288) {
    int n = idx >> 8, k = idx & 255;              // pk is [n][k]
    pkT[(size_t)k * 2048 + n] = f2bf(pk[idx]);    // pkT is [k][n]
  }
}

// ---------------- Kernel 1: grouped conv (queries) + fused x-transpose ------
// R5-best structure (empirical best across R5-R11: 6 structural variants and
// 2 traffic variants all equal or worse). Producer-side transpose retained:
// R11 proved consumer-side (k_xproj strided fp32 staging) costs more than
// the 25MB xbT write it saves.
__global__ __launch_bounds__(256, 2) void k_conv(
    const float* __restrict__ x, const short* __restrict__ wqb,
    short* __restrict__ qo, short* __restrict__ xbT)
{
  __shared__ __align__(16) short Xs[64 * 192];    // swizzled [r][octet^sw(r)]
  const int tid = threadIdx.x, lane = tid & 63, w = tid >> 6;
  const int g = blockIdx.y;
  const int m0 = blockIdx.x * 64;                 // global row (b*2048+n)
  const int wr = (w >> 1) * 32, wcol = (w & 1) * 96;
  const int lrow = lane & 15, g4 = lane >> 4, lk8 = g4 * 8;

  // ---- stage full tile (bf16, swizzled), quad-contiguous 128B chunks ----
  {
    const int r = tid >> 2, q = tid & 3;
    const int sw = (r ^ (r >> 3)) & 7;
    const float* src = x + (size_t)(m0 + r) * 768 + g * 192;
#pragma unroll
    for (int i = 0; i < 6; i++) {
      const int col = i * 32 + q * 8;             // 4 lanes -> 128B contig
      float4 v0 = *(const float4*)(src + col);
      float4 v1 = *(const float4*)(src + col + 4);
      const int o = col >> 3;                     // octet = i*4 + q
      *(short8*)&Xs[r * 192 + ((o ^ sw) << 3)] = cvt8(v0, v1);
    }
  }
  __syncthreads();

  f32x4 acc[2][6];
#pragma unroll
  for (int mi = 0; mi < 2; mi++)
#pragma unroll
    for (int cf = 0; cf < 6; cf++) acc[mi][cf] = (f32x4)0.f;

  const int row0 = wr + lrow, row1 = wr + 16 + lrow;
  const int sw0 = (row0 ^ (row0 >> 3)) & 7;
  const int sw1 = (row1 ^ (row1 >> 3)) & 7;

#pragma unroll
  for (int s = 0; s < 6; s++) {
    const int k0 = s * 32;
    const int ob = (k0 >> 3) + g4;
    short8 a0 = *(const short8*)&Xs[row0 * 192 + ((ob ^ sw0) << 3)];
    short8 a1 = *(const short8*)&Xs[row1 * 192 + ((ob ^ sw1) << 3)];
#pragma unroll
    for (int cf = 0; cf < 6; cf++) {
      short8 bb = *(const short8*)(wqb + ((size_t)g * 192 + wcol + cf * 16 + lrow) * 192 + k0 + lk8);
      acc[0][cf] = MFMA(a0, bb, acc[0][cf]);
      acc[1][cf] = MFMA(a1, bb, acc[1][cf]);
    }
  }

  // ---- queries out ----
#pragma unroll
  for (int mi = 0; mi < 2; mi++)
#pragma unroll
    for (int cf = 0; cf < 6; cf++)
#pragma unroll
      for (int j = 0; j < 4; j++) {
        int m = m0 + wr + mi * 16 + g4 * 4 + j;
        qo[(size_t)m * 768 + g * 192 + wcol + cf * 16 + lrow] = f2bf(acc[mi][cf][j]);
      }

  // ---- transpose write to xbT: xbT[(b*768+e)*2048 + n] ----
  {
    const int b = m0 >> 11, n0 = m0 & 2047;
    const int el = tid >> 3, oct = tid & 7;       // 32 cols x 8 n-octets
#pragma unroll
    for (int ec = 0; ec < 6; ec++) {
      const int c = ec * 32 + el;
      const int o = c >> 3, ci = c & 7;
      short8 v;
#pragma unroll
      for (int u = 0; u < 8; u++) {
        const int n = oct * 8 + u;                // sw(n) = u ^ oct
        v[u] = Xs[n * 192 + (((o ^ (u ^ oct)) << 3)) + ci];
      }
      *(short8*)(xbT + ((size_t)b * 768 + g * 192 + c) * 2048 + n0 + oct * 8) = v;
    }
  }
}

// ---------------- Kernel 2: xproj[b,k2,e] = sum_n pk[n,k2] * x[b,n,e] -------
__global__ __launch_bounds__(512, 4) void k_xproj(
    const short* __restrict__ pkT, const short* __restrict__ xbT,
    float* __restrict__ xproj)
{
  __shared__ __align__(16) short A2[2][64][72];
  __shared__ __align__(16) short B2[2][64][72];
  const int tid = threadIdx.x, lane = tid & 63, w = tid >> 6;
  const int f = blockIdx.x;
  const int xcd = f & 7, rem = f >> 3;
  const int k2t4 = rem & 3, eb8 = rem >> 2;
  const int e_b = eb8 * 8 + xcd;             // [0,96)
  const int k2t = k2t4 * 64;
  const int et = (e_b % 12) * 64, b = e_b / 12;
  const int lrow = lane & 15, g4 = lane >> 4, lk8 = g4 * 8;
  const int wa = (w & 3) * 16, wb = (w >> 2) * 32;

  const int r = tid >> 3, c8 = tid & 7;
  const short* aSrc = pkT + (size_t)(k2t + r) * 2048 + c8 * 8;
  const short* bSrc = xbT + ((size_t)b * 768 + et + r) * 2048 + c8 * 8;

  {
    short8 gA = *(const short8*)aSrc;
    short8 gB = *(const short8*)bSrc;
    *(short8*)&A2[0][r][c8 * 8] = gA;
    *(short8*)&B2[0][r][c8 * 8] = gB;
  }
  __syncthreads();

  f32x4 acc[2];
  acc[0] = (f32x4)0.f; acc[1] = (f32x4)0.f;

  short8 gA, gB;
#pragma unroll 2
  for (int t = 0; t < 32; ++t) {
    const int cur = t & 1;
    if (t < 31) {
      gA = *(const short8*)(aSrc + (t + 1) * 64);
      gB = *(const short8*)(bSrc + (t + 1) * 64);
    }
    short8 af0 = *(const short8*)&A2[cur][wa + lrow][lk8];
    short8 af1 = *(const short8*)&A2[cur][wa + lrow][32 + lk8];
    short8 bf00 = *(const short8*)&B2[cur][wb + lrow][lk8];
    short8 bf01 = *(const short8*)&B2[cur][wb + lrow][32 + lk8];
    short8 bf10 = *(const short8*)&B2[cur][wb + 16 + lrow][lk8];
    short8 bf11 = *(const short8*)&B2[cur][wb + 16 + lrow][32 + lk8];
    acc[0] = MFMA(af0, bf00, acc[0]);
    acc[0] = MFMA(af1, bf01, acc[0]);
    acc[1] = MFMA(af0, bf10, acc[1]);
    acc[1] = MFMA(af1, bf11, acc[1]);
    if (t < 31) {
      *(short8*)&A2[cur ^ 1][r][c8 * 8] = gA;
      *(short8*)&B2[cur ^ 1][r][c8 * 8] = gB;
    }
    __syncthreads();
  }

  float* dst = xproj + ((size_t)b * 256 + k2t + wa) * 768 + et + wb;
#pragma unroll
  for (int cf = 0; cf < 2; cf++)
#pragma unroll
    for (int j = 0; j < 4; j++)
      dst[(size_t)(g4 * 4 + j) * 768 + cf * 16 + lrow] = acc[cf][j];
}

// ---------------- Kernel 2.5: kp = grouped conv_k(xproj), IN-PLACE ----------
__global__ __launch_bounds__(256) void k_kconv(
    float* xpio, const short* __restrict__ wkb)
{
  const int tid = threadIdx.x, lane = tid & 63, w = tid >> 6;
  const int rt = blockIdx.x * 64, g = blockIdx.y, b = blockIdx.z;
  const int wr = (w >> 1) * 32, wcol = (w & 1) * 96;
  const int lrow = lane & 15, g4 = lane >> 4, lk8 = (lane >> 4) * 8;

  f32x4 acc[2][6];
#pragma unroll
  for (int mi = 0; mi < 2; mi++)
#pragma unroll
    for (int cf = 0; cf < 6; cf++) acc[mi][cf] = (f32x4)0.f;

#pragma unroll
  for (int s = 0; s < 6; s++) {
    int k0 = s * 32;
    short8 af[2];
#pragma unroll
    for (int mi = 0; mi < 2; mi++) {
      const float* ap = xpio + ((size_t)b * 256 + rt + wr + mi * 16 + lrow) * 768
                        + g * 192 + k0 + lk8;
      float4 f0 = *(const float4*)ap;
      float4 f1 = *(const float4*)(ap + 4);
      af[mi] = cvt8(f0, f1);
    }
#pragma unroll
    for (int cf = 0; cf < 6; cf++) {
      short8 bb = *(const short8*)(wkb + ((size_t)g * 192 + wcol + cf * 16 + lrow) * 192 + k0 + lk8);
      acc[0][cf] = MFMA(af[0], bb, acc[0][cf]);
      acc[1][cf] = MFMA(af[1], bb, acc[1][cf]);
    }
  }
  __syncthreads();   // all waves' reads of this block's region complete
#pragma unroll
  for (int mi = 0; mi < 2; mi++)
#pragma unroll
    for (int cf = 0; cf < 6; cf++)
#pragma unroll
      for (int j = 0; j < 4; j++) {
        int k2 = rt + wr + mi * 16 + g4 * 4 + j;
        xpio[((size_t)b * 256 + k2) * 768 + g * 192 + wcol + cf * 16 + lrow] =
            acc[mi][cf][j];
      }
}

// ---------------- Kernel 3: gather K/V per (b,h) into bf16 staging ----------
__global__ __launch_bounds__(256) void k_gather(
    const float* __restrict__ kp, short* __restrict__ Kb, short* __restrict__ Vb)
{
  const int h = blockIdx.x, b = blockIdx.y;
  const int bh = b * 12 + h;
  const int tid = threadIdx.x;
  const float* kpb = kp + (size_t)b * 196608;
  {
    const int kb4 = (h & 3) * 64, doff = h >> 2;
    const int dh = tid & 63, kq = tid >> 6;   // kq uniform per wave
    const float* row = kpb + (size_t)(kb4 + dh) * 768 + doff;
    short* dst = Kb + (size_t)bh * 18432 + dh;
#pragma unroll 8
    for (int i = 0; i < 64; i++) {
      int k2 = kq * 64 + i;
      dst[(size_t)k2 * 72] = f2bf(row[3 * k2]);   // coalesced 128B store
    }
  }
  {
    short* dst = Vb + (size_t)bh * 16384;
#pragma unroll
    for (int i = 0; i < 8; i++) {
      int oct = tid + 256 * i;
      int k2h = oct >> 6, dh = oct & 63;        // dh = lane -> coalesced reads
      short8 v;
#pragma unroll
      for (int u = 0; u < 8; u++)
        v[u] = f2bf(kpb[(size_t)(k2h * 8 + u) * 768 + h * 64 + dh]);
      *(short8*)&dst[oct * 8] = v;              // coalesced 16B store
    }
  }
}

// ---------------- Kernel 4: attention per (b,h) -----------------------------
__global__ __launch_bounds__(512, 4) void k_attn(
    const short* __restrict__ qws, const short* __restrict__ Kb,
    const short* __restrict__ Vb, short* __restrict__ ctx)
{
  __shared__ __align__(16) short Kls[18432];   // [k2][72]
  __shared__ __align__(16) short Vls[16384];   // [k2>>3][dh][k2&7]
  const int tid = threadIdx.x, lane = tid & 63, w = tid >> 6;
  const int n0 = blockIdx.x * 128;
  const int h = blockIdx.y, b = blockIdx.z;
  const int bh = b * 12 + h;

  {
    const short8* gk = (const short8*)(Kb + (size_t)bh * 18432);
    short8* lk = (short8*)Kls;
#pragma unroll
    for (int i = 0; i < 4; i++) lk[tid + 512 * i] = gk[tid + 512 * i];
    if (tid < 256) lk[tid + 2048] = gk[tid + 2048];
    const short8* gv = (const short8*)(Vb + (size_t)bh * 16384);
    short8* lv = (short8*)Vls;
#pragma unroll
    for (int i = 0; i < 4; i++) lv[tid + 512 * i] = gv[tid + 512 * i];
  }
  const int lrow = lane & 15, g = lane >> 4, lk8 = g * 8;
  const int nrow = n0 + w * 16;
  const short* qp = qws + ((size_t)b * 2048 + nrow + lrow) * 768 + h * 64;
  short8 bq0 = *(const short8*)(qp + lk8);
  short8 bq1 = *(const short8*)(qp + 32 + lk8);
  __syncthreads();

  f32x4 s[16];
#pragma unroll
  for (int fc = 0; fc < 16; fc++) s[fc] = (f32x4)0.f;
  __builtin_amdgcn_s_setprio(1);
#pragma unroll
  for (int fc = 0; fc < 16; fc++) {
    short8 ak0 = *(const short8*)&Kls[(fc * 16 + lrow) * 72 + lk8];
    short8 ak1 = *(const short8*)&Kls[(fc * 16 + lrow) * 72 + 32 + lk8];
    s[fc] = MFMA(ak0, bq0, s[fc]);
    s[fc] = MFMA(ak1, bq1, s[fc]);
  }
  __builtin_amdgcn_s_setprio(0);

  float mx = -3.0e38f;
#pragma unroll
  for (int fc = 0; fc < 16; fc++)
#pragma unroll
    for (int j = 0; j < 4; j++) mx = fmaxf(mx, s[fc][j]);
  mx = fmaxf(mx, __shfl_xor(mx, 16));
  mx = fmaxf(mx, __shfl_xor(mx, 32));
  float sum = 0.f;
#pragma unroll
  for (int fc = 0; fc < 16; fc++)
#pragma unroll
    for (int j = 0; j < 4; j++) {
      float e = __expf(0.125f * (s[fc][j] - mx));
      s[fc][j] = e; sum += e;
    }
  sum += __shfl_xor(sum, 16);
  sum += __shfl_xor(sum, 32);
  float inv = 1.f / sum;

  unsigned pku[16][2];
#pragma unroll
  for (int fc = 0; fc < 16; fc++) {
    pku[fc][0] = (unsigned)(unsigned short)f2bf(s[fc][0] * inv)
               | ((unsigned)(unsigned short)f2bf(s[fc][1] * inv) << 16);
    pku[fc][1] = (unsigned)(unsigned short)f2bf(s[fc][2] * inv)
               | ((unsigned)(unsigned short)f2bf(s[fc][3] * inv) << 16);
  }

  f32x4 o[4];
#pragma unroll
  for (int fd = 0; fd < 4; fd++) o[fd] = (f32x4)0.f;
  const int L0 = ((lane & 16) << 1) + lrow;   // 32*(g&1) + c
  const int L1 = L0 + 16;
  const bool hi = (lane >= 32);               // fc select = g>>1
  __builtin_amdgcn_s_setprio(1);
#pragma unroll
  for (int t = 0; t < 8; t++) {
    unsigned a0 = (unsigned)__shfl((int)pku[2 * t][0], L0);
    unsigned a1 = (unsigned)__shfl((int)pku[2 * t][1], L0);
    unsigned a2 = (unsigned)__shfl((int)pku[2 * t][0], L1);
    unsigned a3 = (unsigned)__shfl((int)pku[2 * t][1], L1);
    unsigned c0 = (unsigned)__shfl((int)pku[2 * t + 1][0], L0);
    unsigned c1 = (unsigned)__shfl((int)pku[2 * t + 1][1], L0);
    unsigned c2 = (unsigned)__shfl((int)pku[2 * t + 1][0], L1);
    unsigned c3 = (unsigned)__shfl((int)pku[2 * t + 1][1], L1);
    i32x4 bi = { (int)(hi ? c0 : a0), (int)(hi ? c1 : a1),
                 (int)(hi ? c2 : a2), (int)(hi ? c3 : a3) };
    short8 bfrag = __builtin_bit_cast(short8, bi);
#pragma unroll
    for (int fd = 0; fd < 4; fd++) {
      short8 av = *(const short8*)&Vls[((t * 4 + g) * 64 + fd * 16 + lrow) * 8];
      o[fd] = MFMA(av, bfrag, o[fd]);
    }
  }
  __builtin_amdgcn_s_setprio(0);
#pragma unroll
  for (int fd = 0; fd < 4; fd++) {
    short4v st;
#pragma unroll
    for (int j = 0; j < 4; j++) st[j] = f2bf(o[fd][j]);
    *(short4v*)&ctx[((size_t)b * 2048 + n0 + w * 16 + lrow) * 768
                    + h * 64 + fd * 16 + 4 * g] = st;
  }
}

// ---------------- Kernel 5: y = ctx@Wout^T + bias + x  (bf16 y) -------------
// 128x128 tile, BK=32, reg->LDS dbuf. grid 768 = 3 blocks/CU; XCD-swizzled.
__global__ __launch_bounds__(512, 4) void k_gemm_y(
    const short* __restrict__ ctx, const short* __restrict__ woutb,
    const float* __restrict__ bout, const float* __restrict__ x,
    short* __restrict__ ybf)
{
  __shared__ __align__(16) short As[2][128][40];
  __shared__ __align__(16) short Bs[2][128][40];
  const int tid = threadIdx.x, lane = tid & 63, w = tid >> 6;
  const int f = blockIdx.x;
  const int xcd = f & 7, rem = f >> 3;       // rem in [0,96)
  const int mi_l = rem / 6, ni = rem % 6;
  const int m0 = (xcd * 16 + mi_l) * 128;
  const int n0 = ni * 128;
  const int lrow = lane & 15, g4 = lane >> 4, lk8 = g4 * 8;
  const int wr2 = (w >> 2) * 64, wc4 = (w & 3) * 32;

  const int r = tid >> 2, c8 = (tid & 3) * 8;
  const short* aSrc = ctx + (size_t)(m0 + r) * 768 + c8;
  const short* bSrc = woutb + (size_t)(n0 + r) * 768 + c8;

  {
    short8 gA = *(const short8*)aSrc;
    short8 gB = *(const short8*)bSrc;
    *(short8*)&As[0][r][c8] = gA;
    *(short8*)&Bs[0][r][c8] = gB;
  }
  __syncthreads();

  f32x4 acc[4][2];
#pragma unroll
  for (int rf = 0; rf < 4; rf++)
#pragma unroll
    for (int cf = 0; cf < 2; cf++) acc[rf][cf] = (f32x4)0.f;

  short8 gA, gB;
#pragma unroll 2
  for (int t = 0; t < 24; ++t) {
    const int cur = t & 1;
    if (t < 23) {
      gA = *(const short8*)(aSrc + (t + 1) * 32);
      gB = *(const short8*)(bSrc + (t + 1) * 32);
    }
    short8 af[4], bf[2];
#pragma unroll
    for (int rf = 0; rf < 4; rf++)
      af[rf] = *(const short8*)&As[cur][wr2 + rf * 16 + lrow][lk8];
#pragma unroll
    for (int cf = 0; cf < 2; cf++)
      bf[cf] = *(const short8*)&Bs[cur][wc4 + cf * 16 + lrow][lk8];
#pragma unroll
    for (int cf = 0; cf < 2; cf++)
#pragma unroll
      for (int rf = 0; rf < 4; rf++)
        acc[rf][cf] = MFMA(af[rf], bf[cf], acc[rf][cf]);
    if (t < 23) {
      *(short8*)&As[cur ^ 1][r][c8] = gA;
      *(short8*)&Bs[cur ^ 1][r][c8] = gB;
    }
    __syncthreads();
  }

  float cB[2];
#pragma unroll
  for (int cf = 0; cf < 2; cf++) cB[cf] = bout[n0 + wc4 + cf * 16 + lrow];
#pragma unroll
  for (int rf = 0; rf < 4; rf++)
#pragma unroll
    for (int j = 0; j < 4; j++) {
      int row = m0 + wr2 + rf * 16 + g4 * 4 + j;
      const float* xr = x + (size_t)row * 768 + n0 + wc4;
      short* yr = ybf + (size_t)row * 768 + n0 + wc4;
#pragma unroll
      for (int cf = 0; cf < 2; cf++)
        yr[cf * 16 + lrow] = f2bf(acc[rf][cf][j] + cB[cf] + xr[cf * 16 + lrow]);
    }
}

// ---------------- Kernel 6: LayerNorm over bf16 y -> fp32 out ---------------
__global__ __launch_bounds__(256) void k_ln(
    const short* __restrict__ ybf, const float* __restrict__ gamma,
    const float* __restrict__ beta, float* __restrict__ out)
{
  const int tid = threadIdx.x, lane = tid & 63, w = tid >> 6;
  const int half = lane >> 5, l5 = lane & 31;
  const int row = blockIdx.x * 8 + w * 2 + half;
  const short* yr = ybf + (size_t)row * 768;

  float v[24];
  float s1 = 0.f, s2 = 0.f;
#pragma unroll
  for (int j = 0; j < 3; j++) {
    short8 p = *(const short8*)(yr + (l5 + 32 * j) * 8);
#pragma unroll
    for (int u = 0; u < 8; u++) {
      float fv = bf2f(p[u]);
      v[j * 8 + u] = fv;
      s1 += fv; s2 += fv * fv;
    }
  }
  s1 += __shfl_xor(s1, 1, 32);  s2 += __shfl_xor(s2, 1, 32);
  s1 += __shfl_xor(s1, 2, 32);  s2 += __shfl_xor(s2, 2, 32);
  s1 += __shfl_xor(s1, 4, 32);  s2 += __shfl_xor(s2, 4, 32);
  s1 += __shfl_xor(s1, 8, 32);  s2 += __shfl_xor(s2, 8, 32);
  s1 += __shfl_xor(s1, 16, 32); s2 += __shfl_xor(s2, 16, 32);
  float mean = s1 * (1.f / 768.f);
  float var = s2 * (1.f / 768.f) - mean * mean;
  float rstd = rsqrtf(var + 1e-12f);

  float* orow = out + (size_t)row * 768;
#pragma unroll
  for (int j = 0; j < 3; j++) {
    int c0 = (l5 + 32 * j) * 8;
    float4 o0, o1;
    o0.x = (v[j*8+0] - mean) * rstd * gamma[c0+0] + beta[c0+0];
    o0.y = (v[j*8+1] - mean) * rstd * gamma[c0+1] + beta[c0+1];
    o0.z = (v[j*8+2] - mean) * rstd * gamma[c0+2] + beta[c0+2];
    o0.w = (v[j*8+3] - mean) * rstd * gamma[c0+3] + beta[c0+3];
    o1.x = (v[j*8+4] - mean) * rstd * gamma[c0+4] + beta[c0+4];
    o1.y = (v[j*8+5] - mean) * rstd * gamma[c0+5] + beta[c0+5];
    o1.z = (v[j*8+6] - mean) * rstd * gamma[c0+6] + beta[c0+6];
    o1.w = (v[j*8+7] - mean) * rstd * gamma[c0+7] + beta[c0+7];
    *(float4*)(orow + c0) = o0;
    *(float4*)(orow + c0 + 4) = o1;
  }
}

// ---------------- Launch ----------------------------------------------------
extern "C" void kernel_launch(void* const* d_in, const int* in_sizes, int n_in,
                              void* d_out, int out_size, void* d_ws, size_t ws_size,
                              hipStream_t stream)
{
  const float* x     = (const float*)d_in[0];
  const float* wq    = (const float*)d_in[1];
  const float* wk    = (const float*)d_in[2];
  const float* pk    = (const float*)d_in[3];
  const float* wout  = (const float*)d_in[4];
  const float* bout  = (const float*)d_in[5];
  const float* gamma = (const float*)d_in[6];
  const float* beta  = (const float*)d_in[7];
  float* out = (float*)d_out;

  char* ws = (char*)d_ws;
  short* qbf   = (short*)(ws + 0);           // 16384*768*2 = 25165824 (ybf after attn)
  short* xbT   = (short*)(ws + 25165824);    // 25165824 (reused as ctx)
  float* kpbuf = (float*)(ws + 50331648);    // 6291456 (xproj then kp, in-place)
  short* wqb   = (short*)(ws + 56623104);    // 294912
  short* wkb   = (short*)(ws + 56918016);    // 294912
  short* woutb = (short*)(ws + 57212928);    // 1179648
  short* pkT   = (short*)(ws + 58392576);    // 1048576
  if (ws_size < 59441152) return;            // insufficient scratch: clean fail
  short* ctx = (short*)xbT;                  // xbT dead after k_xproj
  short* ybf = qbf;                          // qbf dead after k_attn

  short* Kb = (short*)d_out;                 // staging in d_out (dead after k_attn)
  short* Vb = Kb + 96 * 18432;

  k_prep<<<2304, 256, 0, stream>>>(wq, wk, wout, pk, wqb, wkb, woutb, pkT);
  k_conv<<<dim3(256, 4), 256, 0, stream>>>(x, wqb, qbf, xbT);
  k_xproj<<<384, 512, 0, stream>>>(pkT, xbT, kpbuf);
  k_kconv<<<dim3(4, 4, 8), 256, 0, stream>>>(kpbuf, wkb);
  k_gather<<<dim3(12, 8), 256, 0, stream>>>(kpbuf, Kb, Vb);
  k_attn<<<dim3(16, 12, 8), 512, 0, stream>>>(qbf, Kb, Vb, ctx);
  k_gemm_y<<<768, 512, 0, stream>>>(ctx, woutb, bout, x, ybf);
  k_ln<<<2048, 256, 0, stream>>>(ybf, gamma, beta, out);
}

// Round 13
// 163.250 us; speedup vs baseline: 1.0527x; 1.0142x over previous
//
#include <hip/hip_runtime.h>
#include <hip/hip_bf16.h>

typedef short short8 __attribute__((ext_vector_type(8)));
typedef short short4v __attribute__((ext_vector_type(4)));
typedef int i32x4 __attribute__((ext_vector_type(4)));
typedef float f32x4 __attribute__((ext_vector_type(4)));

#define MFMA(a, b, c) __builtin_amdgcn_mfma_f32_16x16x32_bf16((a), (b), (c), 0, 0, 0)

__device__ __forceinline__ short f2bf(float f) {
  unsigned u = __builtin_bit_cast(unsigned, f);
  unsigned r = u + 0x7FFFu + ((u >> 16) & 1u);
  return (short)(r >> 16);
}

__device__ __forceinline__ float bf2f(short s) {
  unsigned u = ((unsigned)(unsigned short)s) << 16;
  return __builtin_bit_cast(float, u);
}

__device__ __forceinline__ short8 cvt8(float4 a, float4 b) {
  short8 t;
  t[0] = f2bf(a.x); t[1] = f2bf(a.y); t[2] = f2bf(a.z); t[3] = f2bf(a.w);
  t[4] = f2bf(b.x); t[5] = f2bf(b.y); t[6] = f2bf(b.z); t[7] = f2bf(b.w);
  return t;
}

// ---------------- Kernel 0: weight prep only (bf16 casts + pkT) -------------
__global__ __launch_bounds__(256) void k_prep(
    const float* __restrict__ wq, const float* __restrict__ wk,
    const float* __restrict__ wout, const float* __restrict__ pk,
    short* __restrict__ wqb, short* __restrict__ wkb,
    short* __restrict__ woutb, short* __restrict__ pkT)
{
  int idx = blockIdx.x * 256 + threadIdx.x;
  if (idx < 147456) { wqb[idx] = f2bf(wq[idx]); wkb[idx] = f2bf(wk[idx]); }
  if (idx < 589824) { woutb[idx] = f2bf(wout[idx]); }
  if (idx < 524288) {
    int n = idx >> 8, k = idx & 255;              // pk is [n][k]
    pkT[(size_t)k * 2048 + n] = f2bf(pk[idx]);    // pkT is [k][n]
  }
}

// ---------------- Kernel 1: grouped conv (queries) + fused x-transpose ------
// R5-best structure + PINNED load preissue. R8's preload "null" was invalid:
// VGPR_Count=96 proved the compiler sank the 36 wqb loads back to use sites
// (restrict-const loads are freely movable), silently reconstructing the
// serialized load->MFMA chain. sched_barrier(0) after the load block pins
// all 48 global loads (12 x + 36 wqb) to issue up-front: one latency paid,
// not 36. Witness: VGPR_Count must read ~200 (if <=100 the pin failed).
__global__ __launch_bounds__(256, 2) void k_conv(
    const float* __restrict__ x, const short* __restrict__ wqb,
    short* __restrict__ qo, short* __restrict__ xbT)
{
  __shared__ __align__(16) short Xs[64 * 192];    // swizzled [r][octet^sw(r)]
  const int tid = threadIdx.x, lane = tid & 63, w = tid >> 6;
  const int g = blockIdx.y;
  const int m0 = blockIdx.x * 64;                 // global row (b*2048+n)
  const int wr = (w >> 1) * 32, wcol = (w & 1) * 96;
  const int lrow = lane & 15, g4 = lane >> 4, lk8 = g4 * 8;

  // ---- phase 1: ISSUE all 48 global loads (12 x-tile first: critical path) --
  const int r = tid >> 2, q = tid & 3;
  const int sw = (r ^ (r >> 3)) & 7;
  const float* src = x + (size_t)(m0 + r) * 768 + g * 192;
  float4 xv[12];
#pragma unroll
  for (int i = 0; i < 6; i++) {
    const int col = i * 32 + q * 8;               // 4 lanes -> 128B contig
    xv[2 * i]     = *(const float4*)(src + col);
    xv[2 * i + 1] = *(const float4*)(src + col + 4);
  }
  short8 wbb[6][6];
  {
    const short* wp = wqb + ((size_t)g * 192 + wcol + lrow) * 192 + lk8;
#pragma unroll
    for (int s = 0; s < 6; s++)
#pragma unroll
      for (int cf = 0; cf < 6; cf++)
        wbb[s][cf] = *(const short8*)(wp + (size_t)cf * 16 * 192 + s * 32);
  }
  __builtin_amdgcn_sched_barrier(0);   // pin: no load may sink below this

  // ---- phase 2: cvt + LDS write of x tile (xv dies here) ----
#pragma unroll
  for (int i = 0; i < 6; i++) {
    const int col = i * 32 + q * 8;
    const int o = col >> 3;                       // octet = i*4 + q
    *(short8*)&Xs[r * 192 + ((o ^ sw) << 3)] = cvt8(xv[2 * i], xv[2 * i + 1]);
  }
  __syncthreads();

  f32x4 acc[2][6];
#pragma unroll
  for (int mi = 0; mi < 2; mi++)
#pragma unroll
    for (int cf = 0; cf < 6; cf++) acc[mi][cf] = (f32x4)0.f;

  const int row0 = wr + lrow, row1 = wr + 16 + lrow;
  const int sw0 = (row0 ^ (row0 >> 3)) & 7;
  const int sw1 = (row1 ^ (row1 >> 3)) & 7;

#pragma unroll
  for (int s = 0; s < 6; s++) {
    const int ob = s * 4 + g4;
    short8 a0 = *(const short8*)&Xs[row0 * 192 + ((ob ^ sw0) << 3)];
    short8 a1 = *(const short8*)&Xs[row1 * 192 + ((ob ^ sw1) << 3)];
#pragma unroll
    for (int cf = 0; cf < 6; cf++) {
      acc[0][cf] = MFMA(a0, wbb[s][cf], acc[0][cf]);
      acc[1][cf] = MFMA(a1, wbb[s][cf], acc[1][cf]);
    }
  }

  // ---- queries out ----
#pragma unroll
  for (int mi = 0; mi < 2; mi++)
#pragma unroll
    for (int cf = 0; cf < 6; cf++)
#pragma unroll
      for (int j = 0; j < 4; j++) {
        int m = m0 + wr + mi * 16 + g4 * 4 + j;
        qo[(size_t)m * 768 + g * 192 + wcol + cf * 16 + lrow] = f2bf(acc[mi][cf][j]);
      }

  // ---- transpose write to xbT: xbT[(b*768+e)*2048 + n] ----
  {
    const int b = m0 >> 11, n0 = m0 & 2047;
    const int el = tid >> 3, oct = tid & 7;       // 32 cols x 8 n-octets
#pragma unroll
    for (int ec = 0; ec < 6; ec++) {
      const int c = ec * 32 + el;
      const int o = c >> 3, ci = c & 7;
      short8 v;
#pragma unroll
      for (int u = 0; u < 8; u++) {
        const int n = oct * 8 + u;                // sw(n) = u ^ oct
        v[u] = Xs[n * 192 + (((o ^ (u ^ oct)) << 3)) + ci];
      }
      *(short8*)(xbT + ((size_t)b * 768 + g * 192 + c) * 2048 + n0 + oct * 8) = v;
    }
  }
}

// ---------------- Kernel 2: xproj[b,k2,e] = sum_n pk[n,k2] * x[b,n,e] -------
__global__ __launch_bounds__(512, 4) void k_xproj(
    const short* __restrict__ pkT, const short* __restrict__ xbT,
    float* __restrict__ xproj)
{
  __shared__ __align__(16) short A2[2][64][72];
  __shared__ __align__(16) short B2[2][64][72];
  const int tid = threadIdx.x, lane = tid & 63, w = tid >> 6;
  const int f = blockIdx.x;
  const int xcd = f & 7, rem = f >> 3;
  const int k2t4 = rem & 3, eb8 = rem >> 2;
  const int e_b = eb8 * 8 + xcd;             // [0,96)
  const int k2t = k2t4 * 64;
  const int et = (e_b % 12) * 64, b = e_b / 12;
  const int lrow = lane & 15, g4 = lane >> 4, lk8 = g4 * 8;
  const int wa = (w & 3) * 16, wb = (w >> 2) * 32;

  const int r = tid >> 3, c8 = tid & 7;
  const short* aSrc = pkT + (size_t)(k2t + r) * 2048 + c8 * 8;
  const short* bSrc = xbT + ((size_t)b * 768 + et + r) * 2048 + c8 * 8;

  {
    short8 gA = *(const short8*)aSrc;
    short8 gB = *(const short8*)bSrc;
    *(short8*)&A2[0][r][c8 * 8] = gA;
    *(short8*)&B2[0][r][c8 * 8] = gB;
  }
  __syncthreads();

  f32x4 acc[2];
  acc[0] = (f32x4)0.f; acc[1] = (f32x4)0.f;

  short8 gA, gB;
#pragma unroll 2
  for (int t = 0; t < 32; ++t) {
    const int cur = t & 1;
    if (t < 31) {
      gA = *(const short8*)(aSrc + (t + 1) * 64);
      gB = *(const short8*)(bSrc + (t + 1) * 64);
    }
    short8 af0 = *(const short8*)&A2[cur][wa + lrow][lk8];
    short8 af1 = *(const short8*)&A2[cur][wa + lrow][32 + lk8];
    short8 bf00 = *(const short8*)&B2[cur][wb + lrow][lk8];
    short8 bf01 = *(const short8*)&B2[cur][wb + lrow][32 + lk8];
    short8 bf10 = *(const short8*)&B2[cur][wb + 16 + lrow][lk8];
    short8 bf11 = *(const short8*)&B2[cur][wb + 16 + lrow][32 + lk8];
    acc[0] = MFMA(af0, bf00, acc[0]);
    acc[0] = MFMA(af1, bf01, acc[0]);
    acc[1] = MFMA(af0, bf10, acc[1]);
    acc[1] = MFMA(af1, bf11, acc[1]);
    if (t < 31) {
      *(short8*)&A2[cur ^ 1][r][c8 * 8] = gA;
      *(short8*)&B2[cur ^ 1][r][c8 * 8] = gB;
    }
    __syncthreads();
  }

  float* dst = xproj + ((size_t)b * 256 + k2t + wa) * 768 + et + wb;
#pragma unroll
  for (int cf = 0; cf < 2; cf++)
#pragma unroll
    for (int j = 0; j < 4; j++)
      dst[(size_t)(g4 * 4 + j) * 768 + cf * 16 + lrow] = acc[cf][j];
}

// ---------------- Kernel 2.5: kp = grouped conv_k(xproj), IN-PLACE ----------
__global__ __launch_bounds__(256) void k_kconv(
    float* xpio, const short* __restrict__ wkb)
{
  const int tid = threadIdx.x, lane = tid & 63, w = tid >> 6;
  const int rt = blockIdx.x * 64, g = blockIdx.y, b = blockIdx.z;
  const int wr = (w >> 1) * 32, wcol = (w & 1) * 96;
  const int lrow = lane & 15, g4 = lane >> 4, lk8 = (lane >> 4) * 8;

  f32x4 acc[2][6];
#pragma unroll
  for (int mi = 0; mi < 2; mi++)
#pragma unroll
    for (int cf = 0; cf < 6; cf++) acc[mi][cf] = (f32x4)0.f;

#pragma unroll
  for (int s = 0; s < 6; s++) {
    int k0 = s * 32;
    short8 af[2];
#pragma unroll
    for (int mi = 0; mi < 2; mi++) {
      const float* ap = xpio + ((size_t)b * 256 + rt + wr + mi * 16 + lrow) * 768
                        + g * 192 + k0 + lk8;
      float4 f0 = *(const float4*)ap;
      float4 f1 = *(const float4*)(ap + 4);
      af[mi] = cvt8(f0, f1);
    }
#pragma unroll
    for (int cf = 0; cf < 6; cf++) {
      short8 bb = *(const short8*)(wkb + ((size_t)g * 192 + wcol + cf * 16 + lrow) * 192 + k0 + lk8);
      acc[0][cf] = MFMA(af[0], bb, acc[0][cf]);
      acc[1][cf] = MFMA(af[1], bb, acc[1][cf]);
    }
  }
  __syncthreads();   // all waves' reads of this block's region complete
#pragma unroll
  for (int mi = 0; mi < 2; mi++)
#pragma unroll
    for (int cf = 0; cf < 6; cf++)
#pragma unroll
      for (int j = 0; j < 4; j++) {
        int k2 = rt + wr + mi * 16 + g4 * 4 + j;
        xpio[((size_t)b * 256 + k2) * 768 + g * 192 + wcol + cf * 16 + lrow] =
            acc[mi][cf][j];
      }
}

// ---------------- Kernel 3: gather K/V per (b,h) into bf16 staging ----------
__global__ __launch_bounds__(256) void k_gather(
    const float* __restrict__ kp, short* __restrict__ Kb, short* __restrict__ Vb)
{
  const int h = blockIdx.x, b = blockIdx.y;
  const int bh = b * 12 + h;
  const int tid = threadIdx.x;
  const float* kpb = kp + (size_t)b * 196608;
  {
    const int kb4 = (h & 3) * 64, doff = h >> 2;
    const int dh = tid & 63, kq = tid >> 6;   // kq uniform per wave
    const float* row = kpb + (size_t)(kb4 + dh) * 768 + doff;
    short* dst = Kb + (size_t)bh * 18432 + dh;
#pragma unroll 8
    for (int i = 0; i < 64; i++) {
      int k2 = kq * 64 + i;
      dst[(size_t)k2 * 72] = f2bf(row[3 * k2]);   // coalesced 128B store
    }
  }
  {
    short* dst = Vb + (size_t)bh * 16384;
#pragma unroll
    for (int i = 0; i < 8; i++) {
      int oct = tid + 256 * i;
      int k2h = oct >> 6, dh = oct & 63;        // dh = lane -> coalesced reads
      short8 v;
#pragma unroll
      for (int u = 0; u < 8; u++)
        v[u] = f2bf(kpb[(size_t)(k2h * 8 + u) * 768 + h * 64 + dh]);
      *(short8*)&dst[oct * 8] = v;              // coalesced 16B store
    }
  }
}

// ---------------- Kernel 4: attention per (b,h) -----------------------------
__global__ __launch_bounds__(512, 4) void k_attn(
    const short* __restrict__ qws, const short* __restrict__ Kb,
    const short* __restrict__ Vb, short* __restrict__ ctx)
{
  __shared__ __align__(16) short Kls[18432];   // [k2][72]
  __shared__ __align__(16) short Vls[16384];   // [k2>>3][dh][k2&7]
  const int tid = threadIdx.x, lane = tid & 63, w = tid >> 6;
  const int n0 = blockIdx.x * 128;
  const int h = blockIdx.y, b = blockIdx.z;
  const int bh = b * 12 + h;

  {
    const short8* gk = (const short8*)(Kb + (size_t)bh * 18432);
    short8* lk = (short8*)Kls;
#pragma unroll
    for (int i = 0; i < 4; i++) lk[tid + 512 * i] = gk[tid + 512 * i];
    if (tid < 256) lk[tid + 2048] = gk[tid + 2048];
    const short8* gv = (const short8*)(Vb + (size_t)bh * 16384);
    short8* lv = (short8*)Vls;
#pragma unroll
    for (int i = 0; i < 4; i++) lv[tid + 512 * i] = gv[tid + 512 * i];
  }
  const int lrow = lane & 15, g = lane >> 4, lk8 = g * 8;
  const int nrow = n0 + w * 16;
  const short* qp = qws + ((size_t)b * 2048 + nrow + lrow) * 768 + h * 64;
  short8 bq0 = *(const short8*)(qp + lk8);
  short8 bq1 = *(const short8*)(qp + 32 + lk8);
  __syncthreads();

  f32x4 s[16];
#pragma unroll
  for (int fc = 0; fc < 16; fc++) s[fc] = (f32x4)0.f;
  __builtin_amdgcn_s_setprio(1);
#pragma unroll
  for (int fc = 0; fc < 16; fc++) {
    short8 ak0 = *(const short8*)&Kls[(fc * 16 + lrow) * 72 + lk8];
    short8 ak1 = *(const short8*)&Kls[(fc * 16 + lrow) * 72 + 32 + lk8];
    s[fc] = MFMA(ak0, bq0, s[fc]);
    s[fc] = MFMA(ak1, bq1, s[fc]);
  }
  __builtin_amdgcn_s_setprio(0);

  float mx = -3.0e38f;
#pragma unroll
  for (int fc = 0; fc < 16; fc++)
#pragma unroll
    for (int j = 0; j < 4; j++) mx = fmaxf(mx, s[fc][j]);
  mx = fmaxf(mx, __shfl_xor(mx, 16));
  mx = fmaxf(mx, __shfl_xor(mx, 32));
  float sum = 0.f;
#pragma unroll
  for (int fc = 0; fc < 16; fc++)
#pragma unroll
    for (int j = 0; j < 4; j++) {
      float e = __expf(0.125f * (s[fc][j] - mx));
      s[fc][j] = e; sum += e;
    }
  sum += __shfl_xor(sum, 16);
  sum += __shfl_xor(sum, 32);
  float inv = 1.f / sum;

  unsigned pku[16][2];
#pragma unroll
  for (int fc = 0; fc < 16; fc++) {
    pku[fc][0] = (unsigned)(unsigned short)f2bf(s[fc][0] * inv)
               | ((unsigned)(unsigned short)f2bf(s[fc][1] * inv) << 16);
    pku[fc][1] = (unsigned)(unsigned short)f2bf(s[fc][2] * inv)
               | ((unsigned)(unsigned short)f2bf(s[fc][3] * inv) << 16);
  }

  f32x4 o[4];
#pragma unroll
  for (int fd = 0; fd < 4; fd++) o[fd] = (f32x4)0.f;
  const int L0 = ((lane & 16) << 1) + lrow;   // 32*(g&1) + c
  const int L1 = L0 + 16;
  const bool hi = (lane >= 32);               // fc select = g>>1
  __builtin_amdgcn_s_setprio(1);
#pragma unroll
  for (int t = 0; t < 8; t++) {
    unsigned a0 = (unsigned)__shfl((int)pku[2 * t][0], L0);
    unsigned a1 = (unsigned)__shfl((int)pku[2 * t][1], L0);
    unsigned a2 = (unsigned)__shfl((int)pku[2 * t][0], L1);
    unsigned a3 = (unsigned)__shfl((int)pku[2 * t][1], L1);
    unsigned c0 = (unsigned)__shfl((int)pku[2 * t + 1][0], L0);
    unsigned c1 = (unsigned)__shfl((int)pku[2 * t + 1][1], L0);
    unsigned c2 = (unsigned)__shfl((int)pku[2 * t + 1][0], L1);
    unsigned c3 = (unsigned)__shfl((int)pku[2 * t + 1][1], L1);
    i32x4 bi = { (int)(hi ? c0 : a0), (int)(hi ? c1 : a1),
                 (int)(hi ? c2 : a2), (int)(hi ? c3 : a3) };
    short8 bfrag = __builtin_bit_cast(short8, bi);
#pragma unroll
    for (int fd = 0; fd < 4; fd++) {
      short8 av = *(const short8*)&Vls[((t * 4 + g) * 64 + fd * 16 + lrow) * 8];
      o[fd] = MFMA(av, bfrag, o[fd]);
    }
  }
  __builtin_amdgcn_s_setprio(0);
#pragma unroll
  for (int fd = 0; fd < 4; fd++) {
    short4v st;
#pragma unroll
    for (int j = 0; j < 4; j++) st[j] = f2bf(o[fd][j]);
    *(short4v*)&ctx[((size_t)b * 2048 + n0 + w * 16 + lrow) * 768
                    + h * 64 + fd * 16 + 4 * g] = st;
  }
}

// ---------------- Kernel 5: y = ctx@Wout^T + bias + x  (bf16 y) -------------
// 128x128 tile, BK=32, reg->LDS dbuf. grid 768 = 3 blocks/CU; XCD-swizzled.
__global__ __launch_bounds__(512, 4) void k_gemm_y(
    const short* __restrict__ ctx, const short* __restrict__ woutb,
    const float* __restrict__ bout, const float* __restrict__ x,
    short* __restrict__ ybf)
{
  __shared__ __align__(16) short As[2][128][40];
  __shared__ __align__(16) short Bs[2][128][40];
  const int tid = threadIdx.x, lane = tid & 63, w = tid >> 6;
  const int f = blockIdx.x;
  const int xcd = f & 7, rem = f >> 3;       // rem in [0,96)
  const int mi_l = rem / 6, ni = rem % 6;
  const int m0 = (xcd * 16 + mi_l) * 128;
  const int n0 = ni * 128;
  const int lrow = lane & 15, g4 = lane >> 4, lk8 = g4 * 8;
  const int wr2 = (w >> 2) * 64, wc4 = (w & 3) * 32;

  const int r = tid >> 2, c8 = (tid & 3) * 8;
  const short* aSrc = ctx + (size_t)(m0 + r) * 768 + c8;
  const short* bSrc = woutb + (size_t)(n0 + r) * 768 + c8;

  {
    short8 gA = *(const short8*)aSrc;
    short8 gB = *(const short8*)bSrc;
    *(short8*)&As[0][r][c8] = gA;
    *(short8*)&Bs[0][r][c8] = gB;
  }
  __syncthreads();

  f32x4 acc[4][2];
#pragma unroll
  for (int rf = 0; rf < 4; rf++)
#pragma unroll
    for (int cf = 0; cf < 2; cf++) acc[rf][cf] = (f32x4)0.f;

  short8 gA, gB;
#pragma unroll 2
  for (int t = 0; t < 24; ++t) {
    const int cur = t & 1;
    if (t < 23) {
      gA = *(const short8*)(aSrc + (t + 1) * 32);
      gB = *(const short8*)(bSrc + (t + 1) * 32);
    }
    short8 af[4], bf[2];
#pragma unroll
    for (int rf = 0; rf < 4; rf++)
      af[rf] = *(const short8*)&As[cur][wr2 + rf * 16 + lrow][lk8];
#pragma unroll
    for (int cf = 0; cf < 2; cf++)
      bf[cf] = *(const short8*)&Bs[cur][wc4 + cf * 16 + lrow][lk8];
#pragma unroll
    for (int cf = 0; cf < 2; cf++)
#pragma unroll
      for (int rf = 0; rf < 4; rf++)
        acc[rf][cf] = MFMA(af[rf], bf[cf], acc[rf][cf]);
    if (t < 23) {
      *(short8*)&As[cur ^ 1][r][c8] = gA;
      *(short8*)&Bs[cur ^ 1][r][c8] = gB;
    }
    __syncthreads();
  }

  float cB[2];
#pragma unroll
  for (int cf = 0; cf < 2; cf++) cB[cf] = bout[n0 + wc4 + cf * 16 + lrow];
#pragma unroll
  for (int rf = 0; rf < 4; rf++)
#pragma unroll
    for (int j = 0; j < 4; j++) {
      int row = m0 + wr2 + rf * 16 + g4 * 4 + j;
      const float* xr = x + (size_t)row * 768 + n0 + wc4;
      short* yr = ybf + (size_t)row * 768 + n0 + wc4;
#pragma unroll
      for (int cf = 0; cf < 2; cf++)
        yr[cf * 16 + lrow] = f2bf(acc[rf][cf][j] + cB[cf] + xr[cf * 16 + lrow]);
    }
}

// ---------------- Kernel 6: LayerNorm over bf16 y -> fp32 out ---------------
__global__ __launch_bounds__(256) void k_ln(
    const short* __restrict__ ybf, const float* __restrict__ gamma,
    const float* __restrict__ beta, float* __restrict__ out)
{
  const int tid = threadIdx.x, lane = tid & 63, w = tid >> 6;
  const int half = lane >> 5, l5 = lane & 31;
  const int row = blockIdx.x * 8 + w * 2 + half;
  const short* yr = ybf + (size_t)row * 768;

  float v[24];
  float s1 = 0.f, s2 = 0.f;
#pragma unroll
  for (int j = 0; j < 3; j++) {
    short8 p = *(const short8*)(yr + (l5 + 32 * j) * 8);
#pragma unroll
    for (int u = 0; u < 8; u++) {
      float fv = bf2f(p[u]);
      v[j * 8 + u] = fv;
      s1 += fv; s2 += fv * fv;
    }
  }
  s1 += __shfl_xor(s1, 1, 32);  s2 += __shfl_xor(s2, 1, 32);
  s1 += __shfl_xor(s1, 2, 32);  s2 += __shfl_xor(s2, 2, 32);
  s1 += __shfl_xor(s1, 4, 32);  s2 += __shfl_xor(s2, 4, 32);
  s1 += __shfl_xor(s1, 8, 32);  s2 += __shfl_xor(s2, 8, 32);
  s1 += __shfl_xor(s1, 16, 32); s2 += __shfl_xor(s2, 16, 32);
  float mean = s1 * (1.f / 768.f);
  float var = s2 * (1.f / 768.f) - mean * mean;
  float rstd = rsqrtf(var + 1e-12f);

  float* orow = out + (size_t)row * 768;
#pragma unroll
  for (int j = 0; j < 3; j++) {
    int c0 = (l5 + 32 * j) * 8;
    float4 o0, o1;
    o0.x = (v[j*8+0] - mean) * rstd * gamma[c0+0] + beta[c0+0];
    o0.y = (v[j*8+1] - mean) * rstd * gamma[c0+1] + beta[c0+1];
    o0.z = (v[j*8+2] - mean) * rstd * gamma[c0+2] + beta[c0+2];
    o0.w = (v[j*8+3] - mean) * rstd * gamma[c0+3] + beta[c0+3];
    o1.x = (v[j*8+4] - mean) * rstd * gamma[c0+4] + beta[c0+4];
    o1.y = (v[j*8+5] - mean) * rstd * gamma[c0+5] + beta[c0+5];
    o1.z = (v[j*8+6] - mean) * rstd * gamma[c0+6] + beta[c0+6];
    o1.w = (v[j*8+7] - mean) * rstd * gamma[c0+7] + beta[c0+7];
    *(float4*)(orow + c0) = o0;
    *(float4*)(orow + c0 + 4) = o1;
  }
}

// ---------------- Launch ----------------------------------------------------
extern "C" void kernel_launch(void* const* d_in, const int* in_sizes, int n_in,
                              void* d_out, int out_size, void* d_ws, size_t ws_size,
                              hipStream_t stream)
{
  const float* x     = (const float*)d_in[0];
  const float* wq    = (const float*)d_in[1];
  const float* wk    = (const float*)d_in[2];
  const float* pk    = (const float*)d_in[3];
  const float* wout  = (const float*)d_in[4];
  const float* bout  = (const float*)d_in[5];
  const float* gamma = (const float*)d_in[6];
  const float* beta  = (const float*)d_in[7];
  float* out = (float*)d_out;

  char* ws = (char*)d_ws;
  short* qbf   = (short*)(ws + 0);           // 16384*768*2 = 25165824 (ybf after attn)
  short* xbT   = (short*)(ws + 25165824);    // 25165824 (reused as ctx)
  float* kpbuf = (float*)(ws + 50331648);    // 6291456 (xproj then kp, in-place)
  short* wqb   = (short*)(ws + 56623104);    // 294912
  short* wkb   = (short*)(ws + 56918016);    // 294912
  short* woutb = (short*)(ws + 57212928);    // 1179648
  short* pkT   = (short*)(ws + 58392576);    // 1048576
  if (ws_size < 59441152) return;            // insufficient scratch: clean fail
  short* ctx = (short*)xbT;                  // xbT dead after k_xproj
  short* ybf = qbf;                          // qbf dead after k_attn

  short* Kb = (short*)d_out;                 // staging in d_out (dead after k_attn)
  short* Vb = Kb + 96 * 18432;

  k_prep<<<2304, 256, 0, stream>>>(wq, wk, wout, pk, wqb, wkb, woutb, pkT);
  k_conv<<<dim3(256, 4), 256, 0, stream>>>(x, wqb, qbf, xbT);
  k_xproj<<<384, 512, 0, stream>>>(pkT, xbT, kpbuf);
  k_kconv<<<dim3(4, 4, 8), 256, 0, stream>>>(kpbuf, wkb);
  k_gather<<<dim3(12, 8), 256, 0, stream>>>(kpbuf, Kb, Vb);
  k_attn<<<dim3(16, 12, 8), 512, 0, stream>>>(qbf, Kb, Vb, ctx);
  k_gemm_y<<<768, 512, 0, stream>>>(ctx, woutb, bout, x, ybf);
  k_ln<<<2048, 256, 0, stream>>>(ybf, gamma, beta, out);
}